// Round 1
// baseline (747.950 us; speedup 1.0000x reference)
//
#include <hip/hip_runtime.h>
#include <hip/hip_cooperative_groups.h>
#include <stdint.h>

namespace cg = cooperative_groups;

#define BB 4
#define HH 256
#define WW 256
#define CC 128
#define NN 32
#define NPIX (HH*WW)            // 65536
#define RANK 52428u             // 0-based order-stat index: 0.8*(65536-1) exactly
#define TOTAL_PAIRS 1984.0f     // B * N*(N-1)/2
#define CAND_MAX 8192u

// workspace layout
#define OFF_KEYS 0                               // BB*NPIX u32 = 1 MiB
#define OFF_P    (BB*NPIX*4)                     // BB*NPIX i32 = 1 MiB
#define OFF_HIST (OFF_P + BB*NPIX*4)             // BB*1024 u32 = 16 KiB (zeroed)
#define OFF_FINE (OFF_HIST + BB*1024*4)          // BB*64 u32 = 1 KiB  (zeroed)
#define OFF_CNT  (OFF_FINE + BB*64*4)            // BB u32, padded to 64 B (zeroed)
#define OFF_THR  (OFF_CNT + 64)                  // BB u32 (always written)
#define OFF_CAND (OFF_THR + 64)                  // BB*CAND_MAX u32 = 128 KiB
#define ZERO_BYTES (BB*1024*4 + BB*64*4 + 64)

typedef __attribute__((ext_vector_type(8))) short short8;
typedef __attribute__((ext_vector_type(4))) float f32x4;

// 3-way bf16 split via truncation; residual <= 2^-24 |f|.
__device__ __forceinline__ void split3(float f, short &hi, short &mid, short &lo) {
    uint32_t u  = __float_as_uint(f);
    uint32_t hb = u & 0xffff0000u;
    hi = (short)(hb >> 16);
    float r1 = f - __uint_as_float(hb);
    uint32_t mb = __float_as_uint(r1) & 0xffff0000u;
    mid = (short)(mb >> 16);
    float r2 = r1 - __uint_as_float(mb);
    lo = (short)(__float_as_uint(r2) >> 16);
}

// quantized bin: monotone nondecreasing in d2 (x128 exact pow2 scale) -> exact select.
__device__ __forceinline__ uint32_t qbin_of(uint32_t keybits) {
    float f = __uint_as_float(keybits);
    return (uint32_t)fminf(f * 128.0f, 65535.0f);
}

// ---------------- K0: MFMA min squared distance -> keys + coarse hist ----------------
// block = 256 threads = 4 waves; each wave loops 4 tiles of 16 pixels => 256 px/block.
// NEW vs prev version: 1024-bin coarse histogram built from in-register key bits
// (LDS atomics) and merged to global once per block -> deletes selection scan 1.
__global__ __launch_bounds__(256) void k_d2mfma(const float* __restrict__ feat,
        const int* __restrict__ centers, uint32_t* __restrict__ keys,
        uint32_t* __restrict__ hist) {
    __shared__ short gB[12288];      // 24 KiB: [s][tt*4+kk][lane][8]
    __shared__ float gpart[32][8];
    __shared__ float gnormL[32];
    __shared__ uint32_t lhist[1024];
    int b = blockIdx.y;
    int tid = threadIdx.x;

    #pragma unroll
    for (int j = 0; j < 4; j++) lhist[tid + j*256] = 0u;

    // ---- inline gather: thread (n = tid&31, j0 = tid>>5) owns center n, cols [j0*16,+16)
    {
        int n = tid & 31, j0 = tid >> 5;
        int cy = centers[(b*NN + n)*2 + 0];
        int cx = centers[(b*NN + n)*2 + 1];
        const float* gp = feat + ((size_t)(b << 16) + cy*WW + cx)*CC + j0*16;
        int tt = n >> 4, lane16 = n & 15, kk = j0 >> 1, qbase = (j0 & 1)*2;
        float ss = 0.f;
        #pragma unroll
        for (int hh = 0; hh < 2; hh++) {         // two 8-col halves -> q = qbase+hh
            short8 vhi, vmid, vlo;
            #pragma unroll
            for (int u = 0; u < 8; u++) {
                float f = gp[hh*8 + u];
                ss = fmaf(f, f, ss);
                short a, bm, c; split3(f, a, bm, c);
                vhi[u] = a; vmid[u] = bm; vlo[u] = c;
            }
            int lane = (qbase + hh)*16 + lane16;
            int off = (tt*4 + kk)*512 + lane*8;  // shorts; 16B-aligned contiguous
            *(short8*)&gB[off]        = vhi;
            *(short8*)&gB[off + 4096] = vmid;
            *(short8*)&gB[off + 8192] = vlo;
        }
        gpart[n][j0] = ss;
    }
    __syncthreads();
    if (tid < 32) {
        float s = 0.f;
        #pragma unroll
        for (int j = 0; j < 8; j++) s += gpart[tid][j];
        gnormL[tid] = s;
    }
    __syncthreads();

    int wv = tid >> 6, L = tid & 63;
    int m = L & 15, q = L >> 4;
    float gn0 = gnormL[m];
    float gn1 = gnormL[16 + m];

    for (int it = 0; it < 4; it++) {
        int p0 = blockIdx.x*256 + (wv*4 + it)*16;
        const float* fp = feat + ((size_t)(b << 16) + p0 + m)*CC + q*8;

        f32x4 acc[2] = {{0.f,0.f,0.f,0.f},{0.f,0.f,0.f,0.f}};
        float fn = 0.f;

        #pragma unroll
        for (int kk = 0; kk < 4; kk++) {
            float4 fa = *(const float4*)(fp + kk*32);
            float4 fb = *(const float4*)(fp + kk*32 + 4);
            float fs[8] = {fa.x,fa.y,fa.z,fa.w,fb.x,fb.y,fb.z,fb.w};
            short8 ahi, amid, alo;
            #pragma unroll
            for (int j = 0; j < 8; j++) {
                float f = fs[j];
                fn = fmaf(f, f, fn);
                short hh, md, lw; split3(f, hh, md, lw);
                ahi[j] = hh; amid[j] = md; alo[j] = lw;
            }
            #pragma unroll
            for (int t = 0; t < 2; t++) {
                int off = (t*4 + kk)*512 + L*8;
                short8 bhi = *(const short8*)&gB[off];
                short8 bmd = *(const short8*)&gB[off + 4096];
                short8 blo = *(const short8*)&gB[off + 8192];
                // 6 significant split products
                acc[t] = __builtin_amdgcn_mfma_f32_16x16x32_bf16(ahi,  bhi, acc[t], 0,0,0);
                acc[t] = __builtin_amdgcn_mfma_f32_16x16x32_bf16(ahi,  bmd, acc[t], 0,0,0);
                acc[t] = __builtin_amdgcn_mfma_f32_16x16x32_bf16(amid, bhi, acc[t], 0,0,0);
                acc[t] = __builtin_amdgcn_mfma_f32_16x16x32_bf16(ahi,  blo, acc[t], 0,0,0);
                acc[t] = __builtin_amdgcn_mfma_f32_16x16x32_bf16(amid, bmd, acc[t], 0,0,0);
                acc[t] = __builtin_amdgcn_mfma_f32_16x16x32_bf16(alo,  bhi, acc[t], 0,0,0);
            }
        }

        fn += __shfl_xor(fn, 16);
        fn += __shfl_xor(fn, 32);

        // C layout: col(n) = L&15, row(pixel) = q*4 + reg
        float vmin[4];
        #pragma unroll
        for (int r = 0; r < 4; r++) {
            float fnr = __shfl(fn, q*4 + r);
            float d0 = fnr + gn0 - 2.f*acc[0][r];
            float d1 = fnr + gn1 - 2.f*acc[1][r];
            float v = fminf(d0, d1);
            v = fminf(v, __shfl_xor(v, 1));
            v = fminf(v, __shfl_xor(v, 2));
            v = fminf(v, __shfl_xor(v, 4));
            v = fminf(v, __shfl_xor(v, 8));
            vmin[r] = v;
        }
        if (m < 4) {
            float v = (m==0) ? vmin[0] : (m==1) ? vmin[1] : (m==2) ? vmin[2] : vmin[3];
            if (!(v > 0.f)) v = 0.f;     // clamp negatives and -0.0
            uint32_t kb = __float_as_uint(v);
            keys[(size_t)(b << 16) + p0 + q*4 + m] = kb;
            atomicAdd(&lhist[qbin_of(kb) >> 6], 1u);
        }
    }

    __syncthreads();
    #pragma unroll
    for (int j = 0; j < 4; j++) {
        int bin = tid + j*256;
        uint32_t hv = lhist[bin];
        if (hv) atomicAdd(&hist[(b << 10) + bin], hv);
    }
}

// ---------------- union-find helpers ----------------
__device__ __forceinline__ int uf_find(int* P, int x) {
    while (true) {
        int p = P[x];
        if (p == x) return x;
        int gp = P[p];
        if (gp != p) P[x] = gp;   // path halving (benign race)
        x = gp;
    }
}
__device__ __forceinline__ void uf_unite(int* P, int a, int b) {
    while (true) {
        a = uf_find(P, a);
        b = uf_find(P, b);
        if (a == b) return;
        if (a > b) { int t = a; a = b; b = t; }
        int old = atomicCAS(&P[b], b, a);   // device-scope
        if (old == b) return;
        b = old;
    }
}

// ---------------- fused tail: select + init-run + union + pairs (cooperative) ----------
// grid = 1024 blocks x 256 thr (4 blocks/CU co-resident). bid -> (b = bid>>8, rr = bid&255).
// P2a: 32 blocks/batch: redundant coarse prefix -> T1; ONE key pass collecting fine hist +
//      coarse-bin candidates (replaces old scans 2 and 3).
// P2b: 1 block/batch: fine prefix -> T, exact duplicate-safe rank among candidates -> thr.
// P3:  per-row run-start init. P4: vertical/diagonal unions. P5: pairs + output.
__global__ __launch_bounds__(256, 4) void k_tail(const int* __restrict__ centers,
        const uint32_t* __restrict__ keys, const uint32_t* __restrict__ hist,
        uint32_t* __restrict__ fineh, uint32_t* __restrict__ cnt,
        uint32_t* __restrict__ cand, uint32_t* __restrict__ thr_sm,
        int* __restrict__ Pg, float* __restrict__ out) {
    cg::grid_group grid = cg::this_grid();
    int bid = blockIdx.x;
    int b = bid >> 8, rr = bid & 255;
    int tid = threadIdx.x;

    __shared__ uint32_t swsum[4];
    __shared__ uint32_t sT1, sR1, sT, sR2;
    __shared__ int swmax[4];
    __shared__ int ids[BB*NN];
    __shared__ int stotal;

    // ---- P2a: candidate collection (blocks rr < 32 per batch)
    if (rr < 32) {
        // coarse select T1 (redundant per participating block; 4 KiB L2-hot)
        const uint4* hb = (const uint4*)(hist + (b << 10));
        uint4 h = hb[tid];
        uint32_t s = h.x + h.y + h.z + h.w;
        int lane = tid & 63, w = tid >> 6;
        uint32_t inc = s;
        #pragma unroll
        for (int off = 1; off < 64; off <<= 1) {
            uint32_t nb = __shfl_up((int)inc, off);
            if (lane >= off) inc += nb;
        }
        if (lane == 63) swsum[w] = inc;
        __syncthreads();
        uint32_t prew = 0;
        for (int i = 0; i < w; i++) prew += swsum[i];
        uint32_t pre = prew + inc - s;
        uint32_t cs[4] = {h.x, h.y, h.z, h.w};
        #pragma unroll
        for (int j = 0; j < 4; j++) {
            if (pre <= RANK && RANK < pre + cs[j]) { sT1 = 4u*(uint32_t)tid + (uint32_t)j; sR1 = RANK - pre; }
            pre += cs[j];
        }
        __syncthreads();
        uint32_t T1 = sT1;

        const uint4* kb = (const uint4*)(keys + ((size_t)b << 16)) + (rr << 9);
        #pragma unroll
        for (int i = 0; i < 2; i++) {
            uint4 k = kb[tid + i*256];
            uint32_t q;
            #define PROC_KEY(X) { q = qbin_of(X); if ((q >> 6) == T1) { \
                atomicAdd(&fineh[(b << 6) + (q & 63u)], 1u); \
                uint32_t pp = atomicAdd(&cnt[b], 1u); \
                if (pp < CAND_MAX) cand[b*CAND_MAX + pp] = (X); } }
            PROC_KEY(k.x) PROC_KEY(k.y) PROC_KEY(k.z) PROC_KEY(k.w)
            #undef PROC_KEY
        }
    }
    grid.sync();

    // ---- P2b: final select (block rr == 0 per batch; reuses its own sT1/sR1)
    if (rr == 0) {
        uint32_t T1 = sT1, r1 = sR1;
        if (tid < 64) {
            uint32_t s2 = fineh[(b << 6) + tid];
            uint32_t inc2 = s2;
            #pragma unroll
            for (int off = 1; off < 64; off <<= 1) {
                uint32_t nb = __shfl_up((int)inc2, off);
                if (tid >= off) inc2 += nb;
            }
            uint32_t pre2 = inc2 - s2;
            if (pre2 <= r1 && r1 < pre2 + s2) { sT = (T1 << 6) | (uint32_t)tid; sR2 = r1 - pre2; }
        }
        __syncthreads();
        uint32_t T = sT, r2 = sR2;
        uint32_t K = cnt[b]; if (K > CAND_MAX) K = CAND_MAX;
        const uint32_t* cd = cand + b*CAND_MAX;
        for (uint32_t i = tid; i < K; i += 256) {
            uint32_t v = cd[i];
            if (qbin_of(v) != T) continue;
            uint32_t less = 0, eq = 0;
            for (uint32_t j = 0; j < K; j++) {
                uint32_t x = cd[j];
                if (qbin_of(x) == T) { less += (x < v); eq += (x == v); }
            }
            if (less <= r2 && r2 < less + eq) thr_sm[b] = v;   // all writers agree
        }
    }
    grid.sync();

    // ---- P3: init parents as row-run starts (block = one row)
    {
        uint32_t thrv = thr_sm[b];
        int p = (rr << 8) + tid;
        bool msk = keys[((size_t)b << 16) + p] >= thrv;
        int lane = tid & 63, w = tid >> 6;
        int v = msk ? -1 : tid;
        #pragma unroll
        for (int off = 1; off < 64; off <<= 1) {
            int nb = __shfl_up(v, off);
            if (lane >= off) v = max(v, nb);
        }
        if (lane == 63) swmax[w] = v;
        __syncthreads();
        int acc = v;
        for (int i = 0; i < w; i++) acc = max(acc, swmax[i]);
        Pg[((size_t)b << 16) + p] = msk ? ((rr << 8) + acc + 1) : -1;
    }
    grid.sync();

    // ---- P4: vertical/diagonal unions
    if (rr > 0) {
        int* P = Pg + ((size_t)b << 16);
        int p = (rr << 8) + tid;
        if (P[p] != -1) {
            bool ul = (tid > 0)   && P[p-WW-1] != -1;
            bool uu =                P[p-WW]   != -1;
            bool ur = (tid < 255) && P[p-WW+1] != -1;
            if (ul)        uf_unite(P, p, p-WW-1);
            if (uu && !ul) uf_unite(P, p, p-WW);
            if (ur && !uu) uf_unite(P, p, p-WW+1);
        }
    }
    grid.sync();

    // ---- P5: merged pairs at centers + output (block 0)
    if (bid == 0) {
        if (tid == 0) stotal = 0;
        __syncthreads();
        if (tid < BB*NN) {
            int bb = tid >> 5;
            int cy = centers[tid*2 + 0];
            int cx = centers[tid*2 + 1];
            int p = cy*WW + cx;
            const int* P = Pg + ((size_t)bb << 16);
            int id = P[p];
            if (id != -1) {
                int x = p;
                while (true) { int q2 = P[x]; if (q2 == x) break; x = q2; }
                id = x;
            }
            ids[tid] = id;
        }
        __syncthreads();
        int c2 = 0;
        if (tid < BB*NN) {
            int bb = tid >> 5, n = tid & 31;
            int id = ids[tid];
            if (id != -1) for (int j = n+1; j < NN; j++) c2 += (ids[bb*NN + j] == id);
        }
        if (c2) atomicAdd(&stotal, c2);
        __syncthreads();
        if (tid == 0) out[0] = (float)stotal / TOTAL_PAIRS;
    }
}

extern "C" void kernel_launch(void* const* d_in, const int* in_sizes, int n_in,
                              void* d_out, int out_size, void* d_ws, size_t ws_size,
                              hipStream_t stream) {
    const float* feat  = (const float*)d_in[0];
    const int* centers = (const int*)d_in[1];
    float* out         = (float*)d_out;
    char* ws           = (char*)d_ws;

    uint32_t* keys  = (uint32_t*)(ws + OFF_KEYS);
    int*      Pg    = (int*)(ws + OFF_P);
    uint32_t* hist  = (uint32_t*)(ws + OFF_HIST);
    uint32_t* fineh = (uint32_t*)(ws + OFF_FINE);
    uint32_t* cnt   = (uint32_t*)(ws + OFF_CNT);
    uint32_t* thr   = (uint32_t*)(ws + OFF_THR);
    uint32_t* cand  = (uint32_t*)(ws + OFF_CAND);

    hipMemsetAsync(ws + OFF_HIST, 0, ZERO_BYTES, stream);

    dim3 gridPix(NPIX/256, BB);
    k_d2mfma<<<gridPix, 256, 0, stream>>>(feat, centers, keys, hist);

    void* args[] = { (void*)&centers, (void*)&keys, (void*)&hist, (void*)&fineh,
                     (void*)&cnt, (void*)&cand, (void*)&thr, (void*)&Pg, (void*)&out };
    hipLaunchCooperativeKernel((const void*)k_tail, dim3(HH*BB), dim3(256), args, 0u, stream);
}

// Round 2
// 232.810 us; speedup vs baseline: 3.2127x; 3.2127x over previous
//
#include <hip/hip_runtime.h>
#include <stdint.h>

#define BB 4
#define HH 256
#define WW 256
#define CC 128
#define NN 32
#define NPIX (HH*WW)            // 65536
#define RANK 52428u             // 0-based order-stat index: 0.8*(65536-1) exactly
#define TOTAL_PAIRS 1984.0f     // B * N*(N-1)/2
#define CAND_MAX 8192u

// workspace layout
#define OFF_KEYS 0                               // BB*NPIX u32 = 1 MiB
#define OFF_P    (BB*NPIX*4)                     // BB*NPIX i32 = 1 MiB
#define OFF_HIST (OFF_P + BB*NPIX*4)             // BB*1024 u32 = 16 KiB (zeroed)
#define OFF_THR  (OFF_HIST + BB*1024*4)          // BB u32 (always written)
#define ZERO_BYTES (BB*1024*4)

typedef __attribute__((ext_vector_type(8))) short short8;
typedef __attribute__((ext_vector_type(4))) float f32x4;

// 3-way bf16 split via truncation; residual <= 2^-24 |f|.
__device__ __forceinline__ void split3(float f, short &hi, short &mid, short &lo) {
    uint32_t u  = __float_as_uint(f);
    uint32_t hb = u & 0xffff0000u;
    hi = (short)(hb >> 16);
    float r1 = f - __uint_as_float(hb);
    uint32_t mb = __float_as_uint(r1) & 0xffff0000u;
    mid = (short)(mb >> 16);
    float r2 = r1 - __uint_as_float(mb);
    lo = (short)(__float_as_uint(r2) >> 16);
}

// quantized bin: monotone nondecreasing in d2 (x128 exact pow2 scale) -> exact select.
__device__ __forceinline__ uint32_t qbin_of(uint32_t keybits) {
    float f = __uint_as_float(keybits);
    return (uint32_t)fminf(f * 128.0f, 65535.0f);
}

// ---------------- K0: MFMA min squared distance -> keys + coarse hist ----------------
// block = 256 threads = 4 waves; each wave loops 4 tiles of 16 pixels => 256 px/block.
// 1024-bin coarse histogram built from in-register key bits (LDS atomics), merged to
// global once per block -> selection needs no dedicated coarse pass.
__global__ __launch_bounds__(256) void k_d2mfma(const float* __restrict__ feat,
        const int* __restrict__ centers, uint32_t* __restrict__ keys,
        uint32_t* __restrict__ hist) {
    __shared__ short gB[12288];      // 24 KiB: [s][tt*4+kk][lane][8]
    __shared__ float gpart[32][8];
    __shared__ float gnormL[32];
    __shared__ uint32_t lhist[1024];
    int b = blockIdx.y;
    int tid = threadIdx.x;

    #pragma unroll
    for (int j = 0; j < 4; j++) lhist[tid + j*256] = 0u;

    // ---- inline gather: thread (n = tid&31, j0 = tid>>5) owns center n, cols [j0*16,+16)
    {
        int n = tid & 31, j0 = tid >> 5;
        int cy = centers[(b*NN + n)*2 + 0];
        int cx = centers[(b*NN + n)*2 + 1];
        const float* gp = feat + ((size_t)(b << 16) + cy*WW + cx)*CC + j0*16;
        int tt = n >> 4, lane16 = n & 15, kk = j0 >> 1, qbase = (j0 & 1)*2;
        float ss = 0.f;
        #pragma unroll
        for (int hh = 0; hh < 2; hh++) {         // two 8-col halves -> q = qbase+hh
            short8 vhi, vmid, vlo;
            #pragma unroll
            for (int u = 0; u < 8; u++) {
                float f = gp[hh*8 + u];
                ss = fmaf(f, f, ss);
                short a, bm, c; split3(f, a, bm, c);
                vhi[u] = a; vmid[u] = bm; vlo[u] = c;
            }
            int lane = (qbase + hh)*16 + lane16;
            int off = (tt*4 + kk)*512 + lane*8;  // shorts; 16B-aligned contiguous
            *(short8*)&gB[off]        = vhi;
            *(short8*)&gB[off + 4096] = vmid;
            *(short8*)&gB[off + 8192] = vlo;
        }
        gpart[n][j0] = ss;
    }
    __syncthreads();
    if (tid < 32) {
        float s = 0.f;
        #pragma unroll
        for (int j = 0; j < 8; j++) s += gpart[tid][j];
        gnormL[tid] = s;
    }
    __syncthreads();

    int wv = tid >> 6, L = tid & 63;
    int m = L & 15, q = L >> 4;
    float gn0 = gnormL[m];
    float gn1 = gnormL[16 + m];

    for (int it = 0; it < 4; it++) {
        int p0 = blockIdx.x*256 + (wv*4 + it)*16;
        const float* fp = feat + ((size_t)(b << 16) + p0 + m)*CC + q*8;

        f32x4 acc[2] = {{0.f,0.f,0.f,0.f},{0.f,0.f,0.f,0.f}};
        float fn = 0.f;

        #pragma unroll
        for (int kk = 0; kk < 4; kk++) {
            float4 fa = *(const float4*)(fp + kk*32);
            float4 fb = *(const float4*)(fp + kk*32 + 4);
            float fs[8] = {fa.x,fa.y,fa.z,fa.w,fb.x,fb.y,fb.z,fb.w};
            short8 ahi, amid, alo;
            #pragma unroll
            for (int j = 0; j < 8; j++) {
                float f = fs[j];
                fn = fmaf(f, f, fn);
                short hh, md, lw; split3(f, hh, md, lw);
                ahi[j] = hh; amid[j] = md; alo[j] = lw;
            }
            #pragma unroll
            for (int t = 0; t < 2; t++) {
                int off = (t*4 + kk)*512 + L*8;
                short8 bhi = *(const short8*)&gB[off];
                short8 bmd = *(const short8*)&gB[off + 4096];
                short8 blo = *(const short8*)&gB[off + 8192];
                // 6 significant split products
                acc[t] = __builtin_amdgcn_mfma_f32_16x16x32_bf16(ahi,  bhi, acc[t], 0,0,0);
                acc[t] = __builtin_amdgcn_mfma_f32_16x16x32_bf16(ahi,  bmd, acc[t], 0,0,0);
                acc[t] = __builtin_amdgcn_mfma_f32_16x16x32_bf16(amid, bhi, acc[t], 0,0,0);
                acc[t] = __builtin_amdgcn_mfma_f32_16x16x32_bf16(ahi,  blo, acc[t], 0,0,0);
                acc[t] = __builtin_amdgcn_mfma_f32_16x16x32_bf16(amid, bmd, acc[t], 0,0,0);
                acc[t] = __builtin_amdgcn_mfma_f32_16x16x32_bf16(alo,  bhi, acc[t], 0,0,0);
            }
        }

        fn += __shfl_xor(fn, 16);
        fn += __shfl_xor(fn, 32);

        // C layout: col(n) = L&15, row(pixel) = q*4 + reg
        float vmin[4];
        #pragma unroll
        for (int r = 0; r < 4; r++) {
            float fnr = __shfl(fn, q*4 + r);
            float d0 = fnr + gn0 - 2.f*acc[0][r];
            float d1 = fnr + gn1 - 2.f*acc[1][r];
            float v = fminf(d0, d1);
            v = fminf(v, __shfl_xor(v, 1));
            v = fminf(v, __shfl_xor(v, 2));
            v = fminf(v, __shfl_xor(v, 4));
            v = fminf(v, __shfl_xor(v, 8));
            vmin[r] = v;
        }
        if (m < 4) {
            float v = (m==0) ? vmin[0] : (m==1) ? vmin[1] : (m==2) ? vmin[2] : vmin[3];
            if (!(v > 0.f)) v = 0.f;     // clamp negatives and -0.0
            uint32_t kb = __float_as_uint(v);
            keys[(size_t)(b << 16) + p0 + q*4 + m] = kb;
            atomicAdd(&lhist[qbin_of(kb) >> 6], 1u);
        }
    }

    __syncthreads();
    #pragma unroll
    for (int j = 0; j < 4; j++) {
        int bin = tid + j*256;
        uint32_t hv = lhist[bin];
        if (hv) atomicAdd(&hist[(b << 10) + bin], hv);
    }
}

// ---------------- K1: single-pass select -> exact threshold key bits ----------------
// one block (1024 thr) per batch. Coarse select from precomputed hist (no key pass),
// then ONE key pass collecting fine hist + coarse-bin candidates simultaneously,
// then compact bin-T candidates (~30) and exact duplicate-safe rank among them.
__global__ __launch_bounds__(1024) void k_selthr(const uint32_t* __restrict__ keys,
        const uint32_t* __restrict__ hist, uint32_t* __restrict__ thr_sm) {
    int b = blockIdx.x, t = threadIdx.x;
    __shared__ uint32_t wsum[16];
    __shared__ uint32_t sT1, sR1, sT, sR2, scnt, scnt2;
    __shared__ uint32_t fh[64];
    __shared__ uint32_t cand[CAND_MAX];
    __shared__ uint32_t cand2[2048];

    if (t < 64) fh[t] = 0;
    if (t == 0) { scnt = 0; scnt2 = 0; }

    // coarse select T1: prefix over 1024 precomputed bins (wave scan + cross-wave fix)
    int lane = t & 63, w = t >> 6;
    uint32_t s = hist[(b << 10) + t];
    uint32_t inc = s;
    #pragma unroll
    for (int off = 1; off < 64; off <<= 1) {
        uint32_t nb = __shfl_up((int)inc, off);
        if (lane >= off) inc += nb;
    }
    if (lane == 63) wsum[w] = inc;
    __syncthreads();
    if (t < 16) {
        uint32_t v = wsum[t];
        #pragma unroll
        for (int off = 1; off < 16; off <<= 1) {
            uint32_t nb = __shfl_up((int)v, off);
            if (t >= off) v += nb;
        }
        wsum[t] = v;
    }
    __syncthreads();
    uint32_t pre = ((w == 0) ? 0u : wsum[w-1]) + inc - s;
    if (pre <= RANK && RANK < pre + s) { sT1 = (uint32_t)t; sR1 = RANK - pre; }
    __syncthreads();
    uint32_t T1 = sT1, r1 = sR1;

    // single pass: fine hist (qbin&63) + candidate collection for qbin>>6 == T1
    const uint4* kb = (const uint4*)(keys + ((size_t)b << 16));
    for (int i = t; i < NPIX/4; i += 1024) {
        uint4 k = kb[i];
        uint32_t q;
        #define PROC_KEY(X) { q = qbin_of(X); if ((q >> 6) == T1) { \
            atomicAdd(&fh[q & 63u], 1u); \
            uint32_t p = atomicAdd(&scnt, 1u); \
            if (p < CAND_MAX) cand[p] = (X); } }
        PROC_KEY(k.x) PROC_KEY(k.y) PROC_KEY(k.z) PROC_KEY(k.w)
        #undef PROC_KEY
    }
    __syncthreads();

    // fine select T
    if (t < 64) {
        uint32_t s2 = fh[t];
        uint32_t inc2 = s2;
        #pragma unroll
        for (int off = 1; off < 64; off <<= 1) {
            uint32_t nb = __shfl_up((int)inc2, off);
            if (t >= off) inc2 += nb;
        }
        uint32_t pre2 = inc2 - s2;
        if (pre2 <= r1 && r1 < pre2 + s2) { sT = (T1 << 6) | (uint32_t)t; sR2 = r1 - pre2; }
    }
    __syncthreads();
    uint32_t T = sT, r2 = sR2;
    uint32_t K = scnt; if (K > CAND_MAX) K = CAND_MAX;

    // compact bin-T candidates (expected ~tens)
    for (uint32_t i = t; i < K; i += 1024) {
        uint32_t v = cand[i];
        if (qbin_of(v) == T) { uint32_t p = atomicAdd(&scnt2, 1u); if (p < 2048u) cand2[p] = v; }
    }
    __syncthreads();
    uint32_t K2 = scnt2; if (K2 > 2048u) K2 = 2048u;

    // exact rank among bin-T candidates (duplicate-safe)
    for (uint32_t i = t; i < K2; i += 1024) {
        uint32_t v = cand2[i];
        uint32_t less = 0, eq = 0;
        for (uint32_t j = 0; j < K2; j++) { uint32_t x = cand2[j]; less += (x < v); eq += (x == v); }
        if (less <= r2 && r2 < less + eq) thr_sm[b] = v;   // all writers agree
    }
}

// ---------------- K2: init parents as row-run starts (horizontal unions free) ----------
__global__ __launch_bounds__(256) void k_initrun(const uint32_t* __restrict__ keys,
        const uint32_t* __restrict__ thr_sm, int* __restrict__ P) {
    int b = blockIdx.y;
    int row = blockIdx.x, x = threadIdx.x;   // block = one image row
    int p = row*256 + x;
    uint32_t thr = thr_sm[b];
    bool msk = keys[(b << 16) + p] >= thr;

    __shared__ int wmax[4];
    int lane = x & 63, w = x >> 6;
    int v = msk ? -1 : x;
    #pragma unroll
    for (int off = 1; off < 64; off <<= 1) {
        int nb = __shfl_up(v, off);
        if (lane >= off) v = max(v, nb);
    }
    if (lane == 63) wmax[w] = v;
    __syncthreads();
    int acc = v;
    for (int i = 0; i < w; i++) acc = max(acc, wmax[i]);
    P[(b << 16) + p] = msk ? (row*256 + acc + 1) : -1;
}

// ---------------- K3: union-find CCL — vertical/diagonal merges only ----------------
__device__ __forceinline__ int uf_find(int* P, int x) {
    while (true) {
        int p = P[x];
        if (p == x) return x;
        int gp = P[p];
        if (gp != p) P[x] = gp;   // path halving (benign race)
        x = gp;
    }
}
__device__ __forceinline__ void uf_unite(int* P, int a, int b) {
    while (true) {
        a = uf_find(P, a);
        b = uf_find(P, b);
        if (a == b) return;
        if (a > b) { int t = a; a = b; b = t; }
        int old = atomicCAS(&P[b], b, a);   // device-scope
        if (old == b) return;
        b = old;
    }
}
__global__ __launch_bounds__(256) void k_union(int* __restrict__ Pg) {
    int b = blockIdx.y;
    int p = blockIdx.x*256 + threadIdx.x;
    int* P = Pg + (b << 16);
    if (P[p] == -1) return;
    int y = p >> 8, x = p & 255;
    if (y == 0) return;
    bool ul = (x > 0)   && P[p-WW-1] != -1;
    bool uu =              P[p-WW]   != -1;
    bool ur = (x < 255) && P[p-WW+1] != -1;
    if (ul)        uf_unite(P, p, p-WW-1);
    if (uu && !ul) uf_unite(P, p, p-WW);
    if (ur && !uu) uf_unite(P, p, p-WW+1);
}

// ---------------- K4: merged pairs at centers + output ----------------
__global__ void k_pairs_fin(const int* __restrict__ centers, int* __restrict__ Pg,
                            float* __restrict__ out) {
    __shared__ int ids[BB*NN];
    __shared__ int total;
    int t = threadIdx.x;
    if (t == 0) total = 0;
    __syncthreads();
    if (t < BB*NN) {
        int b = t >> 5;
        int cy = centers[t*2 + 0];
        int cx = centers[t*2 + 1];
        int p = cy*WW + cx;
        const int* P = Pg + (b << 16);
        int id = P[p];
        if (id != -1) {
            int x = p;
            while (true) { int q = P[x]; if (q == x) break; x = q; }
            id = x;
        }
        ids[t] = id;
    }
    __syncthreads();
    int cnt = 0;
    if (t < BB*NN) {
        int b = t >> 5, n = t & 31;
        int id = ids[t];
        if (id != -1) for (int j = n+1; j < NN; j++) cnt += (ids[b*NN + j] == id);
    }
    if (cnt) atomicAdd(&total, cnt);
    __syncthreads();
    if (t == 0) out[0] = (float)total / TOTAL_PAIRS;
}

extern "C" void kernel_launch(void* const* d_in, const int* in_sizes, int n_in,
                              void* d_out, int out_size, void* d_ws, size_t ws_size,
                              hipStream_t stream) {
    const float* feat  = (const float*)d_in[0];
    const int* centers = (const int*)d_in[1];
    float* out         = (float*)d_out;
    char* ws           = (char*)d_ws;

    uint32_t* keys = (uint32_t*)(ws + OFF_KEYS);
    int*      Pg   = (int*)(ws + OFF_P);
    uint32_t* hist = (uint32_t*)(ws + OFF_HIST);
    uint32_t* thr  = (uint32_t*)(ws + OFF_THR);

    hipMemsetAsync(ws + OFF_HIST, 0, ZERO_BYTES, stream);

    dim3 gridPix(NPIX/256, BB);
    k_d2mfma    <<<gridPix, 256, 0, stream>>>(feat, centers, keys, hist);
    k_selthr    <<<BB, 1024, 0, stream>>>(keys, hist, thr);
    k_initrun   <<<gridPix, 256, 0, stream>>>(keys, thr, Pg);
    k_union     <<<gridPix, 256, 0, stream>>>(Pg);
    k_pairs_fin <<<1, 256, 0, stream>>>(centers, Pg, out);
}